// Round 1
// baseline (355.226 us; speedup 1.0000x reference)
//
#include <hip/hip_runtime.h>

#define HID    64
#define HEADS  8
#define MOL_N  40
#define PRO_N  400
#define NGRAPH 256

__device__ __forceinline__ float elu_plus(float x, float c) {
    // elu(x) + c, alpha=1
    return x > 0.0f ? x + c : __expf(x) - 1.0f + c;
}

// ---------------------------------------------------------------------------
// Kernel 1: per-node projections.
//   mol side: mol_s[m,h] = mol_feats[m,:] @ sigma_w[:64,h] + sigma_b[h]
//             mol_m[m,h] = mol_feats[m,:] @ mu_w[:64,h]    + mu_b[h]
//   pro side: pro = pro_feats * spatial
//             pro_s[p,h] = pro @ sigma_w[64:,h];  pro_m[p,h] = pro @ mu_w[64:,h]
// One block = 32 rows, 256 threads (8 threads/row = one (row,head) each).
// Block 0 additionally zeroes the per-graph accumulator.
// ---------------------------------------------------------------------------
__global__ __launch_bounds__(256) void proj_kernel(
    const float* __restrict__ mol_feats, const float* __restrict__ pro_feats,
    const float* __restrict__ spatial,   const float* __restrict__ sigma_w,
    const float* __restrict__ sigma_b,   const float* __restrict__ mu_w,
    const float* __restrict__ mu_b,
    float* __restrict__ mol_s, float* __restrict__ mol_m,
    float* __restrict__ pro_s, float* __restrict__ pro_m,
    float* __restrict__ y_acc, int mol_blocks)
{
    __shared__ float rows[32][HID + 1];     // +1 pad: breaks 32-bank aliasing
    __shared__ float wsig[HID][HEADS];
    __shared__ float wmu [HID][HEADS];

    const int tid = threadIdx.x;
    const bool is_mol = (int)blockIdx.x < mol_blocks;

    if (blockIdx.x == 0) {
        for (int i = tid; i < NGRAPH * HEADS; i += 256) y_acc[i] = 0.0f;
    }

    // stage weights (mol: rows [0,64); pro: rows [64,128))
    const int wofs = is_mol ? 0 : HID * HEADS;
    for (int i = tid; i < HID * HEADS; i += 256) {
        wsig[i / HEADS][i % HEADS] = sigma_w[wofs + i];
        wmu [i / HEADS][i % HEADS] = mu_w  [wofs + i];
    }

    // stage 32 input rows (float4-vectorized, coalesced)
    const int r0 = (is_mol ? (int)blockIdx.x : ((int)blockIdx.x - mol_blocks)) * 32;
    if (is_mol) {
        const float4* src = (const float4*)mol_feats + (size_t)r0 * (HID / 4);
        for (int i = tid; i < 32 * (HID / 4); i += 256) {
            float4 v = src[i];
            int lr = i / (HID / 4), k4 = (i % (HID / 4)) * 4;
            rows[lr][k4 + 0] = v.x; rows[lr][k4 + 1] = v.y;
            rows[lr][k4 + 2] = v.z; rows[lr][k4 + 3] = v.w;
        }
    } else {
        const float4* srcp = (const float4*)pro_feats + (size_t)r0 * (HID / 4);
        const float4* srcs = (const float4*)spatial   + (size_t)r0 * (HID / 4);
        for (int i = tid; i < 32 * (HID / 4); i += 256) {
            float4 a = srcp[i];
            float4 b = srcs[i];
            int lr = i / (HID / 4), k4 = (i % (HID / 4)) * 4;
            rows[lr][k4 + 0] = a.x * b.x; rows[lr][k4 + 1] = a.y * b.y;
            rows[lr][k4 + 2] = a.z * b.z; rows[lr][k4 + 3] = a.w * b.w;
        }
    }
    __syncthreads();

    const int lr = tid >> 3;      // local row
    const int h  = tid & 7;       // head
    float as = 0.0f, am = 0.0f;
#pragma unroll
    for (int k = 0; k < HID; ++k) {
        float x = rows[lr][k];
        as += x * wsig[k][h];
        am += x * wmu [k][h];
    }
    const int gr = r0 + lr;
    if (is_mol) {
        mol_s[gr * HEADS + h] = as + sigma_b[h];   // fold biases into mol side
        mol_m[gr * HEADS + h] = am + mu_b[h];
    } else {
        pro_s[gr * HEADS + h] = as;
        pro_m[gr * HEADS + h] = am;
    }
}

// ---------------------------------------------------------------------------
// Kernel 2: edge map + mu segment-sum.
// One block per mol atom m (grid = M). Edge e = m*400 + j, pro row = b*400+j.
//   mu[e,h]    = elu(mol_m[m,h] + pro_m[p,h]) + 1.0
//   sigma[e,h] = elu(mol_s[m,h] + pro_s[p,h]) + 1.1
// Each thread handles float4 chunks (4 heads); parity of tid fixes head half.
// mu partial sums -> shfl butterfly -> shared -> one atomicAdd per head/block.
// ---------------------------------------------------------------------------
__global__ __launch_bounds__(256) void edge_kernel(
    const float* __restrict__ mol_s, const float* __restrict__ mol_m,
    const float* __restrict__ pro_s, const float* __restrict__ pro_m,
    float* __restrict__ mu_out, float* __restrict__ sg_out,
    float* __restrict__ y_acc)
{
    const int m   = blockIdx.x;
    const int b   = m / MOL_N;
    const int tid = threadIdx.x;

    __shared__ float s_mol[16];    // [0:8) = mol_s row, [8:16) = mol_m row
    __shared__ float s_hsum[HEADS];
    if (tid < 8)       s_mol[tid] = mol_s[m * HEADS + tid];
    else if (tid < 16) s_mol[tid] = mol_m[m * HEADS + (tid - 8)];
    if (tid < HEADS)   s_hsum[tid] = 0.0f;
    __syncthreads();

    const int q = tid & 1;         // head half: heads q*4 .. q*4+3
    float ms[4], mm[4];
#pragma unroll
    for (int k = 0; k < 4; ++k) {
        ms[k] = s_mol[q * 4 + k];
        mm[k] = s_mol[8 + q * 4 + k];
    }

    const float4* pm4 = (const float4*)pro_m + (size_t)b * PRO_N * 2;
    const float4* ps4 = (const float4*)pro_s + (size_t)b * PRO_N * 2;
    float4* mu4 = (float4*)mu_out + (size_t)m * PRO_N * 2;
    float4* sg4 = (float4*)sg_out + (size_t)m * PRO_N * 2;

    float acc[4] = {0.f, 0.f, 0.f, 0.f};
    for (int t = tid; t < PRO_N * 2; t += 256) {   // t = j*2 + q, q constant/thread
        float4 p = pm4[t];
        float4 v;
        v.x = elu_plus(p.x + mm[0], 1.0f);
        v.y = elu_plus(p.y + mm[1], 1.0f);
        v.z = elu_plus(p.z + mm[2], 1.0f);
        v.w = elu_plus(p.w + mm[3], 1.0f);
        mu4[t] = v;
        acc[0] += v.x; acc[1] += v.y; acc[2] += v.z; acc[3] += v.w;
    }
    for (int t = tid; t < PRO_N * 2; t += 256) {
        float4 p = ps4[t];
        float4 v;
        v.x = elu_plus(p.x + ms[0], 1.1f);
        v.y = elu_plus(p.y + ms[1], 1.1f);
        v.z = elu_plus(p.z + ms[2], 1.1f);
        v.w = elu_plus(p.w + ms[3], 1.1f);
        sg4[t] = v;
    }

    // reduce mu partials: butterfly over lanes of same parity (masks 2..32)
#pragma unroll
    for (int mask = 2; mask < 64; mask <<= 1) {
#pragma unroll
        for (int k = 0; k < 4; ++k) acc[k] += __shfl_xor(acc[k], mask, 64);
    }
    if ((tid & 63) < 2) {          // lane 0 (heads 0-3) and lane 1 (heads 4-7)
#pragma unroll
        for (int k = 0; k < 4; ++k) atomicAdd(&s_hsum[q * 4 + k], acc[k]);
    }
    __syncthreads();
    if (tid < HEADS) atomicAdd(&y_acc[b * HEADS + tid], s_hsum[tid]);
}

// ---------------------------------------------------------------------------
// Kernel 3: per-graph MLP head. One thread per graph.
//   y = elu(0.001 * y_acc @ w1 + b1);  y_pred = y @ w2 + b2
// ---------------------------------------------------------------------------
__global__ __launch_bounds__(256) void head_kernel(
    const float* __restrict__ y_acc, const float* __restrict__ w1,
    const float* __restrict__ b1,    const float* __restrict__ w2,
    const float* __restrict__ b2,    float* __restrict__ y_pred)
{
    const int g = threadIdx.x;
    float y[HEADS];
#pragma unroll
    for (int h = 0; h < HEADS; ++h) y[h] = y_acc[g * HEADS + h] * 0.001f;
    float out = b2[0];
#pragma unroll
    for (int o = 0; o < 2 * HEADS; ++o) {
        float a = b1[o];
#pragma unroll
        for (int h = 0; h < HEADS; ++h) a += y[h] * w1[h * (2 * HEADS) + o];
        a = a > 0.0f ? a : __expf(a) - 1.0f;   // elu
        out += a * w2[o];
    }
    y_pred[g] = out;
}

extern "C" void kernel_launch(void* const* d_in, const int* in_sizes, int n_in,
                              void* d_out, int out_size, void* d_ws, size_t ws_size,
                              hipStream_t stream) {
    const float* mol_feats = (const float*)d_in[0];
    const float* pro_feats = (const float*)d_in[1];
    const float* spatial   = (const float*)d_in[2];
    const float* sigma_w   = (const float*)d_in[3];
    const float* sigma_b   = (const float*)d_in[4];
    const float* mu_w      = (const float*)d_in[5];
    const float* mu_b      = (const float*)d_in[6];
    const float* w1        = (const float*)d_in[7];
    const float* b1        = (const float*)d_in[8];
    const float* w2        = (const float*)d_in[9];
    const float* b2        = (const float*)d_in[10];

    const int M = in_sizes[0] / HID;    // 10240
    const int P = in_sizes[1] / HID;    // 102400
    const int E = in_sizes[11];         // 4,096,000 (mol_index length)

    // workspace layout (all float, 16B-aligned slices)
    float* ws    = (float*)d_ws;
    float* mol_s = ws;                         // M*8
    float* mol_m = mol_s + (size_t)M * HEADS;  // M*8
    float* pro_s = mol_m + (size_t)M * HEADS;  // P*8
    float* pro_m = pro_s + (size_t)P * HEADS;  // P*8
    float* y_acc = pro_m + (size_t)P * HEADS;  // NGRAPH*8

    float* mu_out = (float*)d_out;
    float* sg_out = mu_out + (size_t)E * HEADS;
    float* y_pred = sg_out + (size_t)E * HEADS;

    const int mol_blocks = M / 32;
    const int pro_blocks = P / 32;

    proj_kernel<<<mol_blocks + pro_blocks, 256, 0, stream>>>(
        mol_feats, pro_feats, spatial, sigma_w, sigma_b, mu_w, mu_b,
        mol_s, mol_m, pro_s, pro_m, y_acc, mol_blocks);

    edge_kernel<<<M, 256, 0, stream>>>(
        mol_s, mol_m, pro_s, pro_m, mu_out, sg_out, y_acc);

    head_kernel<<<1, 256, 0, stream>>>(y_acc, w1, b1, w2, b2, y_pred);
}

// Round 2
// 353.938 us; speedup vs baseline: 1.0036x; 1.0036x over previous
//
#include <hip/hip_runtime.h>

#define HID    64
#define HEADS  8
#define MOL_N  40
#define PRO_N  400
#define NGRAPH 256

typedef float vfloat4 __attribute__((ext_vector_type(4)));

__device__ __forceinline__ float elu_plus(float x, float c) {
    // elu(x) + c, alpha=1
    return x > 0.0f ? x + c : __expf(x) - 1.0f + c;
}

// ---------------------------------------------------------------------------
// Kernel 1: per-node projections (unchanged from R1 — measured fine).
//   mol side: mol_s[m,h] = mol_feats[m,:] @ sigma_w[:64,h] + sigma_b[h]
//             mol_m[m,h] = mol_feats[m,:] @ mu_w[:64,h]    + mu_b[h]
//   pro side: pro = pro_feats * spatial
//             pro_s[p,h] = pro @ sigma_w[64:,h];  pro_m[p,h] = pro @ mu_w[64:,h]
// One block = 32 rows, 256 threads (8 threads/row = one (row,head) each).
// Block 0 additionally zeroes the per-graph accumulator.
// ---------------------------------------------------------------------------
__global__ __launch_bounds__(256) void proj_kernel(
    const float* __restrict__ mol_feats, const float* __restrict__ pro_feats,
    const float* __restrict__ spatial,   const float* __restrict__ sigma_w,
    const float* __restrict__ sigma_b,   const float* __restrict__ mu_w,
    const float* __restrict__ mu_b,
    float* __restrict__ mol_s, float* __restrict__ mol_m,
    float* __restrict__ pro_s, float* __restrict__ pro_m,
    float* __restrict__ y_acc, int mol_blocks)
{
    __shared__ float rows[32][HID + 1];     // +1 pad: breaks 32-bank aliasing
    __shared__ float wsig[HID][HEADS];
    __shared__ float wmu [HID][HEADS];

    const int tid = threadIdx.x;
    const bool is_mol = (int)blockIdx.x < mol_blocks;

    if (blockIdx.x == 0) {
        for (int i = tid; i < NGRAPH * HEADS; i += 256) y_acc[i] = 0.0f;
    }

    // stage weights (mol: rows [0,64); pro: rows [64,128))
    const int wofs = is_mol ? 0 : HID * HEADS;
    for (int i = tid; i < HID * HEADS; i += 256) {
        wsig[i / HEADS][i % HEADS] = sigma_w[wofs + i];
        wmu [i / HEADS][i % HEADS] = mu_w  [wofs + i];
    }

    // stage 32 input rows (float4-vectorized, coalesced)
    const int r0 = (is_mol ? (int)blockIdx.x : ((int)blockIdx.x - mol_blocks)) * 32;
    if (is_mol) {
        const float4* src = (const float4*)mol_feats + (size_t)r0 * (HID / 4);
        for (int i = tid; i < 32 * (HID / 4); i += 256) {
            float4 v = src[i];
            int lr = i / (HID / 4), k4 = (i % (HID / 4)) * 4;
            rows[lr][k4 + 0] = v.x; rows[lr][k4 + 1] = v.y;
            rows[lr][k4 + 2] = v.z; rows[lr][k4 + 3] = v.w;
        }
    } else {
        const float4* srcp = (const float4*)pro_feats + (size_t)r0 * (HID / 4);
        const float4* srcs = (const float4*)spatial   + (size_t)r0 * (HID / 4);
        for (int i = tid; i < 32 * (HID / 4); i += 256) {
            float4 a = srcp[i];
            float4 b = srcs[i];
            int lr = i / (HID / 4), k4 = (i % (HID / 4)) * 4;
            rows[lr][k4 + 0] = a.x * b.x; rows[lr][k4 + 1] = a.y * b.y;
            rows[lr][k4 + 2] = a.z * b.z; rows[lr][k4 + 3] = a.w * b.w;
        }
    }
    __syncthreads();

    const int lr = tid >> 3;      // local row
    const int h  = tid & 7;       // head
    float as = 0.0f, am = 0.0f;
#pragma unroll
    for (int k = 0; k < HID; ++k) {
        float x = rows[lr][k];
        as += x * wsig[k][h];
        am += x * wmu [k][h];
    }
    const int gr = r0 + lr;
    if (is_mol) {
        mol_s[gr * HEADS + h] = as + sigma_b[h];   // fold biases into mol side
        mol_m[gr * HEADS + h] = am + mu_b[h];
    } else {
        pro_s[gr * HEADS + h] = as;
        pro_m[gr * HEADS + h] = am;
    }
}

// ---------------------------------------------------------------------------
// Kernel 2: edge map + mu segment-sum.  Grid = 256 complexes * 40 atoms, but
// SWIZZLED: b = blockIdx & 255, r = blockIdx >> 8.  Round-robin XCD dispatch
// (xcd = blockIdx % 8) then puts all 40 blocks of complex b on ONE XCD
// (b % 8), so its 51.2 KB projection table stays in that XCD's L2.
// Per-XCD working set: 32 complexes * 51.2 KB = 1.6 MB < 4 MB L2.
// mu+sigma fused in one loop (2 loads + 2 NT stores in flight).
// Non-temporal stores: 262 MB output stream must not write-allocate in L2
// and evict the reused projection tables.
// ---------------------------------------------------------------------------
__global__ __launch_bounds__(256) void edge_kernel(
    const float* __restrict__ mol_s, const float* __restrict__ mol_m,
    const float* __restrict__ pro_s, const float* __restrict__ pro_m,
    float* __restrict__ mu_out, float* __restrict__ sg_out,
    float* __restrict__ y_acc)
{
    const int bi  = blockIdx.x;
    const int b   = bi & (NGRAPH - 1);   // complex id
    const int r   = bi >> 8;             // atom within complex
    const int m   = b * MOL_N + r;       // global mol row
    const int tid = threadIdx.x;

    __shared__ float s_mol[16];    // [0:8) = mol_s row, [8:16) = mol_m row
    __shared__ float s_hsum[HEADS];
    if (tid < 8)       s_mol[tid] = mol_s[m * HEADS + tid];
    else if (tid < 16) s_mol[tid] = mol_m[m * HEADS + (tid - 8)];
    if (tid < HEADS)   s_hsum[tid] = 0.0f;
    __syncthreads();

    const int q = tid & 1;         // head half: heads q*4 .. q*4+3
    float ms[4], mm[4];
#pragma unroll
    for (int k = 0; k < 4; ++k) {
        ms[k] = s_mol[q * 4 + k];
        mm[k] = s_mol[8 + q * 4 + k];
    }

    const vfloat4* pm4 = (const vfloat4*)pro_m + (size_t)b * PRO_N * 2;
    const vfloat4* ps4 = (const vfloat4*)pro_s + (size_t)b * PRO_N * 2;
    vfloat4* mu4 = (vfloat4*)mu_out + (size_t)m * PRO_N * 2;
    vfloat4* sg4 = (vfloat4*)sg_out + (size_t)m * PRO_N * 2;

    float acc[4] = {0.f, 0.f, 0.f, 0.f};
    for (int t = tid; t < PRO_N * 2; t += 256) {   // t = j*2 + q, q constant/thread
        vfloat4 pmv = pm4[t];
        vfloat4 psv = ps4[t];
        vfloat4 vmu, vsg;
        vmu.x = elu_plus(pmv.x + mm[0], 1.0f);
        vmu.y = elu_plus(pmv.y + mm[1], 1.0f);
        vmu.z = elu_plus(pmv.z + mm[2], 1.0f);
        vmu.w = elu_plus(pmv.w + mm[3], 1.0f);
        vsg.x = elu_plus(psv.x + ms[0], 1.1f);
        vsg.y = elu_plus(psv.y + ms[1], 1.1f);
        vsg.z = elu_plus(psv.z + ms[2], 1.1f);
        vsg.w = elu_plus(psv.w + ms[3], 1.1f);
        __builtin_nontemporal_store(vmu, &mu4[t]);
        __builtin_nontemporal_store(vsg, &sg4[t]);
        acc[0] += vmu.x; acc[1] += vmu.y; acc[2] += vmu.z; acc[3] += vmu.w;
    }

    // reduce mu partials: butterfly over lanes of same parity (masks 2..32)
#pragma unroll
    for (int mask = 2; mask < 64; mask <<= 1) {
#pragma unroll
        for (int k = 0; k < 4; ++k) acc[k] += __shfl_xor(acc[k], mask, 64);
    }
    if ((tid & 63) < 2) {          // lane 0 (heads 0-3) and lane 1 (heads 4-7)
#pragma unroll
        for (int k = 0; k < 4; ++k) atomicAdd(&s_hsum[q * 4 + k], acc[k]);
    }
    __syncthreads();
    if (tid < HEADS) atomicAdd(&y_acc[b * HEADS + tid], s_hsum[tid]);
}

// ---------------------------------------------------------------------------
// Kernel 3: per-graph MLP head. One thread per graph.
//   y = elu(0.001 * y_acc @ w1 + b1);  y_pred = y @ w2 + b2
// ---------------------------------------------------------------------------
__global__ __launch_bounds__(256) void head_kernel(
    const float* __restrict__ y_acc, const float* __restrict__ w1,
    const float* __restrict__ b1,    const float* __restrict__ w2,
    const float* __restrict__ b2,    float* __restrict__ y_pred)
{
    const int g = threadIdx.x;
    float y[HEADS];
#pragma unroll
    for (int h = 0; h < HEADS; ++h) y[h] = y_acc[g * HEADS + h] * 0.001f;
    float out = b2[0];
#pragma unroll
    for (int o = 0; o < 2 * HEADS; ++o) {
        float a = b1[o];
#pragma unroll
        for (int h = 0; h < HEADS; ++h) a += y[h] * w1[h * (2 * HEADS) + o];
        a = a > 0.0f ? a : __expf(a) - 1.0f;   // elu
        out += a * w2[o];
    }
    y_pred[g] = out;
}

extern "C" void kernel_launch(void* const* d_in, const int* in_sizes, int n_in,
                              void* d_out, int out_size, void* d_ws, size_t ws_size,
                              hipStream_t stream) {
    const float* mol_feats = (const float*)d_in[0];
    const float* pro_feats = (const float*)d_in[1];
    const float* spatial   = (const float*)d_in[2];
    const float* sigma_w   = (const float*)d_in[3];
    const float* sigma_b   = (const float*)d_in[4];
    const float* mu_w      = (const float*)d_in[5];
    const float* mu_b      = (const float*)d_in[6];
    const float* w1        = (const float*)d_in[7];
    const float* b1        = (const float*)d_in[8];
    const float* w2        = (const float*)d_in[9];
    const float* b2        = (const float*)d_in[10];

    const int M = in_sizes[0] / HID;    // 10240
    const int P = in_sizes[1] / HID;    // 102400
    const int E = in_sizes[11];         // 4,096,000 (mol_index length)

    // workspace layout (all float, 16B-aligned slices)
    float* ws    = (float*)d_ws;
    float* mol_s = ws;                         // M*8
    float* mol_m = mol_s + (size_t)M * HEADS;  // M*8
    float* pro_s = mol_m + (size_t)M * HEADS;  // P*8
    float* pro_m = pro_s + (size_t)P * HEADS;  // P*8
    float* y_acc = pro_m + (size_t)P * HEADS;  // NGRAPH*8

    float* mu_out = (float*)d_out;
    float* sg_out = mu_out + (size_t)E * HEADS;
    float* y_pred = sg_out + (size_t)E * HEADS;

    const int mol_blocks = M / 32;
    const int pro_blocks = P / 32;

    proj_kernel<<<mol_blocks + pro_blocks, 256, 0, stream>>>(
        mol_feats, pro_feats, spatial, sigma_w, sigma_b, mu_w, mu_b,
        mol_s, mol_m, pro_s, pro_m, y_acc, mol_blocks);

    edge_kernel<<<M, 256, 0, stream>>>(
        mol_s, mol_m, pro_s, pro_m, mu_out, sg_out, y_acc);

    head_kernel<<<1, 256, 0, stream>>>(y_acc, w1, b1, w2, b2, y_pred);
}